// Round 1
// baseline (874.091 us; speedup 1.0000x reference)
//
#include <hip/hip_runtime.h>
#include <hip/hip_bf16.h>
#include <math.h>

#define NTOK 8192
#define DDIM 1024
#define HDIM 4096
#define NEXP 8
#define KTOP 2
#define MAXROWS 17408   /* 16384 + 8*128 */
#define MAXTILES 136

typedef __bf16 bf16x8 __attribute__((ext_vector_type(8)));
typedef float f32x4 __attribute__((ext_vector_type(4)));

#define GAS __attribute__((address_space(1)))
#define LAS __attribute__((address_space(3)))

__device__ __forceinline__ void async16(const void* g, void* l) {
  __builtin_amdgcn_global_load_lds((GAS void*)g, (LAS void*)l, 16, 0, 0);
}

// ---------------- workspace layout (bytes) ----------------
#define XB_OFF     ((size_t)0)
#define W1T_OFF    (XB_OFF + (size_t)NTOK*DDIM*2)
#define ROWOUT_OFF W1T_OFF              /* w1t dead after gemm1; rowout 35.7MB < 64MB */
#define W2T_OFF    (W1T_OFF + (size_t)NEXP*DDIM*HDIM*2)
#define HB_OFF     (W2T_OFF + (size_t)NEXP*HDIM*DDIM*2)
#define ROWTOK_OFF (HB_OFF + (size_t)MAXROWS*HDIM*2)
#define ROWW_OFF   (ROWTOK_OFF + (size_t)MAXROWS*4)
#define TOKE_OFF   (ROWW_OFF + (size_t)MAXROWS*4)
#define TOKW_OFF   (TOKE_OFF + (size_t)NTOK*KTOP*4)
#define TOKROW_OFF (TOKW_OFF + (size_t)NTOK*KTOP*4)
#define TILEE_OFF  (TOKROW_OFF + (size_t)NTOK*KTOP*4)
#define CNT_OFF    (TILEE_OFF + (size_t)256*4)
#define POS_OFF    (CNT_OFF + 64)
#define IMP_OFF    (POS_OFF + 64)
#define META_OFF   (IMP_OFF + 64)

// ---------------- small utility kernels ----------------
__global__ void init_kernel(int* counts, float* importance) {
  if (threadIdx.x < NEXP) { counts[threadIdx.x] = 0; importance[threadIdx.x] = 0.f; }
}

__global__ void cast_x_kernel(const float* __restrict__ src, __hip_bfloat16* __restrict__ dst) {
  size_t i = ((size_t)blockIdx.x * blockDim.x + threadIdx.x) * 4;
  if (i < (size_t)NTOK * DDIM) {
    float4 v = *(const float4*)(src + i);
    dst[i + 0] = __float2bfloat16(v.x);
    dst[i + 1] = __float2bfloat16(v.y);
    dst[i + 2] = __float2bfloat16(v.z);
    dst[i + 3] = __float2bfloat16(v.w);
  }
}

// per-expert transpose+cast: src [E][R][C] fp32 -> dst [E][C][R] bf16
__global__ __launch_bounds__(256) void transpose_cast_kernel(
    const float* __restrict__ src, __hip_bfloat16* __restrict__ dst, int R, int C) {
  __shared__ float tile[64][65];
  const int e = blockIdx.z;
  const float* s = src + (size_t)e * R * C;
  __hip_bfloat16* d = dst + (size_t)e * R * C;
  const int c0 = blockIdx.x * 64, r0 = blockIdx.y * 64;
  const int tc = (threadIdx.x & 15) * 4;
  const int tr = threadIdx.x >> 4;
#pragma unroll
  for (int p = 0; p < 4; ++p) {
    float4 v = *(const float4*)&s[(size_t)(r0 + tr + p * 16) * C + c0 + tc];
    tile[tr + p * 16][tc + 0] = v.x;
    tile[tr + p * 16][tc + 1] = v.y;
    tile[tr + p * 16][tc + 2] = v.z;
    tile[tr + p * 16][tc + 3] = v.w;
  }
  __syncthreads();
  const int oc = threadIdx.x >> 4;
  const int orr = (threadIdx.x & 15) * 4;
#pragma unroll
  for (int p = 0; p < 4; ++p) {
    const int c = oc + p * 16;
    __hip_bfloat16 tmp[4];
    tmp[0] = __float2bfloat16(tile[orr + 0][c]);
    tmp[1] = __float2bfloat16(tile[orr + 1][c]);
    tmp[2] = __float2bfloat16(tile[orr + 2][c]);
    tmp[3] = __float2bfloat16(tile[orr + 3][c]);
    *(ushort4*)&d[(size_t)(c0 + c) * R + r0 + orr] = *(ushort4*)tmp;
  }
}

// ---------------- gating ----------------
__global__ __launch_bounds__(256) void gating_kernel(
    const float* __restrict__ x, const float* __restrict__ Wg, const float* __restrict__ bg,
    int* __restrict__ tok_e, float* __restrict__ tok_w,
    int* __restrict__ counts, float* __restrict__ importance) {
  const int tid = threadIdx.x, wid = tid >> 6, lane = tid & 63;
  const int t = blockIdx.x * 32 + wid * 8 + (lane >> 3);
  const int e = lane & 7;
  const float* xr = x + (size_t)t * DDIM;
  double dot = 0.0;
  for (int d = 0; d < DDIM; d += 4) {
    float4 xv = *(const float4*)(xr + d);
    dot += (double)xv.x * (double)Wg[(d + 0) * NEXP + e];
    dot += (double)xv.y * (double)Wg[(d + 1) * NEXP + e];
    dot += (double)xv.z * (double)Wg[(d + 2) * NEXP + e];
    dot += (double)xv.w * (double)Wg[(d + 3) * NEXP + e];
  }
  double logit = dot + (double)bg[e];
  double m = logit;
  for (int off = 1; off < 8; off <<= 1) {
    double o = __shfl_xor(m, off, 64);
    m = o > m ? o : m;
  }
  double p = exp(logit - m);
  double s = p;
  for (int off = 1; off < 8; off <<= 1) s += __shfl_xor(s, off, 64);
  float prob = (float)(p / s);

  __shared__ float imp[NEXP];
  __shared__ int cnt[NEXP];
  if (tid < NEXP) { imp[tid] = 0.f; cnt[tid] = 0; }
  __syncthreads();
  atomicAdd(&imp[e], prob);

  float bp = prob; int be = e;
  for (int off = 1; off < 8; off <<= 1) {
    float op = __shfl_xor(bp, off, 64); int oe = __shfl_xor(be, off, 64);
    if (op > bp || (op == bp && oe < be)) { bp = op; be = oe; }
  }
  float p2 = (e == be) ? -1.f : prob;
  float sp = p2; int se = e;
  for (int off = 1; off < 8; off <<= 1) {
    float op = __shfl_xor(sp, off, 64); int oe = __shfl_xor(se, off, 64);
    if (op > sp || (op == sp && oe < se)) { sp = op; se = oe; }
  }
  if (e == 0) {
    float tsum = bp + sp;
    tok_e[t * 2 + 0] = be; tok_e[t * 2 + 1] = se;
    tok_w[t * 2 + 0] = bp / tsum; tok_w[t * 2 + 1] = sp / tsum;
    atomicAdd(&cnt[be], 1); atomicAdd(&cnt[se], 1);
  }
  __syncthreads();
  if (tid < NEXP) {
    atomicAdd(&counts[tid], cnt[tid]);
    atomicAdd(&importance[tid], imp[tid]);
  }
}

// ---------------- routing ----------------
__global__ void offsets_kernel(const int* __restrict__ counts, int* pos, int* tile_expert,
                               int* meta, int* row_token) {
  if (threadIdx.x == 0) {
    int pb = 0, tb = 0;
    for (int e = 0; e < NEXP; e++) {
      pos[e] = pb;
      int tiles = (counts[e] + 127) >> 7;
      for (int tt = 0; tt < tiles; ++tt) tile_expert[tb + tt] = e;
      pb += tiles * 128; tb += tiles;
    }
    meta[0] = tb;
  }
  __syncthreads();
  for (int i = threadIdx.x; i < MAXROWS; i += blockDim.x) row_token[i] = -1;
}

__global__ void scatter_kernel(const int* __restrict__ tok_e, const float* __restrict__ tok_w,
                               int* __restrict__ pos, int* __restrict__ row_token,
                               float* __restrict__ row_weight, int* __restrict__ tok_row) {
  __shared__ int lcnt[NEXP], lbase[NEXP];
  const int t = blockIdx.x * 256 + threadIdx.x;
  if (threadIdx.x < NEXP) lcnt[threadIdx.x] = 0;
  __syncthreads();
  const int e0 = tok_e[t * 2 + 0], e1 = tok_e[t * 2 + 1];
  const int s0 = atomicAdd(&lcnt[e0], 1);
  const int s1 = atomicAdd(&lcnt[e1], 1);
  __syncthreads();
  if (threadIdx.x < NEXP) lbase[threadIdx.x] = atomicAdd(&pos[threadIdx.x], lcnt[threadIdx.x]);
  __syncthreads();
  int r0 = lbase[e0] + s0; row_token[r0] = t; row_weight[r0] = tok_w[t * 2 + 0]; tok_row[t * 2 + 0] = r0;
  int r1 = lbase[e1] + s1; row_token[r1] = t; row_weight[r1] = tok_w[t * 2 + 1]; tok_row[t * 2 + 1] = r1;
}

// ---------------- GEMM1: h = relu(x @ W1[e] + b1[e]) ----------------
// 4-deep LDS ring, stage distance 2, counted vmcnt(8), raw s_barrier (no drain),
// setprio around MFMA cluster. 64 KiB LDS -> 2 blocks/CU.
__global__ __launch_bounds__(256) void gemm1_kernel(
    const __hip_bfloat16* __restrict__ xb, const __hip_bfloat16* __restrict__ w1t,
    const float* __restrict__ b1, __hip_bfloat16* __restrict__ hb,
    const int* __restrict__ row_token, const int* __restrict__ tile_expert,
    const int* __restrict__ meta) {
  const int tile_y = blockIdx.y;
  if (tile_y >= meta[0]) return;
  const int n0 = blockIdx.x * 128;
  const int e = tile_expert[tile_y];
  const int r0 = tile_y * 128;
  const int tid = threadIdx.x;
  const int wid = tid >> 6, lane = tid & 63;

  __shared__ __align__(16) __hip_bfloat16 As[4][128 * 32];
  __shared__ __align__(16) __hip_bfloat16 Bs[4][128 * 32];

  const int srow = wid * 32 + (lane >> 2);
  const int g = ((lane & 3) ^ (srow & 3)) * 8;   // swizzled 16B group (elements)
  int t0 = row_token[r0 + srow];      if (t0 < 0) t0 = 0;
  int t1 = row_token[r0 + srow + 16]; if (t1 < 0) t1 = 0;
  const __hip_bfloat16* ga0 = xb + (size_t)t0 * DDIM + g;
  const __hip_bfloat16* ga1 = xb + (size_t)t1 * DDIM + g;
  const __hip_bfloat16* gb0 = w1t + ((size_t)e * HDIM + n0 + srow) * DDIM + g;
  const __hip_bfloat16* gb1 = gb0 + (size_t)16 * DDIM;
  const int ldsA0 = (wid * 32) * 32, ldsA1 = (wid * 32 + 16) * 32;

  f32x4 acc[4][4] = {};
  const int wm = (wid & 1) * 64, wn = (wid >> 1) * 64;
  const int fr = lane & 15;
  const int soff = ((lane >> 4) ^ (lane & 3)) * 8;
  const int NT = DDIM / 32;   // 32 K-tiles

#define STAGE1(b) do { \
    async16(ga0, &As[b][ldsA0]); async16(ga1, &As[b][ldsA1]); \
    async16(gb0, &Bs[b][ldsA0]); async16(gb1, &Bs[b][ldsA1]); } while (0)
#define ADV1 do { ga0 += 32; ga1 += 32; gb0 += 32; gb1 += 32; } while (0)

  STAGE1(0); ADV1;
  STAGE1(1); ADV1;
  for (int kt = 0; kt < NT; ++kt) {
    STAGE1((kt + 2) & 3);            // distance-2 prefetch; targets buffer last read at kt-2
    if (kt + 3 < NT) ADV1;           // tail iterations re-stage last tile into dead buffers
    // wait for tile kt only (leaves kt+1, kt+2 = 8 loads in flight across the barrier)
    asm volatile("s_waitcnt vmcnt(8)" ::: "memory");
    __builtin_amdgcn_s_barrier();    // raw barrier: no vmcnt(0) drain
    asm volatile("" ::: "memory");
    __builtin_amdgcn_sched_barrier(0);
    const int cur = kt & 3;
    bf16x8 av[4], bv[4];
#pragma unroll
    for (int i = 0; i < 4; i++) av[i] = *(const bf16x8*)&As[cur][(wm + i * 16 + fr) * 32 + soff];
#pragma unroll
    for (int j = 0; j < 4; j++) bv[j] = *(const bf16x8*)&Bs[cur][(wn + j * 16 + fr) * 32 + soff];
    __builtin_amdgcn_s_setprio(1);
#pragma unroll
    for (int i = 0; i < 4; i++)
#pragma unroll
      for (int j = 0; j < 4; j++)
        acc[i][j] = __builtin_amdgcn_mfma_f32_16x16x32_bf16(av[i], bv[j], acc[i][j], 0, 0, 0);
    __builtin_amdgcn_s_setprio(0);
    __builtin_amdgcn_sched_barrier(0);
  }
#undef STAGE1
#undef ADV1
  asm volatile("s_waitcnt vmcnt(0)" ::: "memory");   // drain leftover prefetches

  const int crow = (lane >> 4) * 4;
  const int ccol = lane & 15;
#pragma unroll
  for (int j = 0; j < 4; j++) {
    const int gc = n0 + wn + j * 16 + ccol;
    const float bias = b1[e * HDIM + gc];
#pragma unroll
    for (int i = 0; i < 4; i++) {
      const int grb = r0 + wm + i * 16 + crow;
#pragma unroll
      for (int r = 0; r < 4; r++) {
        float v = acc[i][j][r] + bias;
        v = v > 0.f ? v : 0.f;
        hb[(size_t)(grb + r) * HDIM + gc] = __float2bfloat16(v);
      }
    }
  }
}

// ---------------- GEMM2: rowout[r] = h[r] @ W2[e] + b2[e], same pipeline, XCD-swizzled ----------------
__global__ __launch_bounds__(256) void gemm2_kernel(
    const __hip_bfloat16* __restrict__ hb, const __hip_bfloat16* __restrict__ w2t,
    const float* __restrict__ b2, __hip_bfloat16* __restrict__ rowout,
    const int* __restrict__ tile_expert, const int* __restrict__ meta) {
  // 1D grid, MAXTILES%8==0: all 8 column-blocks of a row-tile share id%8 -> same XCD
  const int tile_y = blockIdx.x % MAXTILES;
  const int cx = blockIdx.x / MAXTILES;
  if (tile_y >= meta[0]) return;
  const int n0 = cx * 128;
  const int e = tile_expert[tile_y];
  const int r0 = tile_y * 128;
  const int tid = threadIdx.x;
  const int wid = tid >> 6, lane = tid & 63;

  __shared__ __align__(16) __hip_bfloat16 As[4][128 * 32];
  __shared__ __align__(16) __hip_bfloat16 Bs[4][128 * 32];

  const int srow = wid * 32 + (lane >> 2);
  const int g = ((lane & 3) ^ (srow & 3)) * 8;
  const __hip_bfloat16* ga0 = hb + ((size_t)r0 + srow) * HDIM + g;
  const __hip_bfloat16* ga1 = ga0 + (size_t)16 * HDIM;
  const __hip_bfloat16* gb0 = w2t + ((size_t)e * DDIM + n0 + srow) * HDIM + g;
  const __hip_bfloat16* gb1 = gb0 + (size_t)16 * HDIM;
  const int ldsA0 = (wid * 32) * 32, ldsA1 = (wid * 32 + 16) * 32;

  f32x4 acc[4][4] = {};
  const int wm = (wid & 1) * 64, wn = (wid >> 1) * 64;
  const int fr = lane & 15;
  const int soff = ((lane >> 4) ^ (lane & 3)) * 8;
  const int NT = HDIM / 32;   // 128 K-tiles

#define STAGE2(b) do { \
    async16(ga0, &As[b][ldsA0]); async16(ga1, &As[b][ldsA1]); \
    async16(gb0, &Bs[b][ldsA0]); async16(gb1, &Bs[b][ldsA1]); } while (0)
#define ADV2 do { ga0 += 32; ga1 += 32; gb0 += 32; gb1 += 32; } while (0)

  STAGE2(0); ADV2;
  STAGE2(1); ADV2;
  for (int kt = 0; kt < NT; ++kt) {
    STAGE2((kt + 2) & 3);
    if (kt + 3 < NT) ADV2;
    asm volatile("s_waitcnt vmcnt(8)" ::: "memory");
    __builtin_amdgcn_s_barrier();
    asm volatile("" ::: "memory");
    __builtin_amdgcn_sched_barrier(0);
    const int cur = kt & 3;
    bf16x8 av[4], bv[4];
#pragma unroll
    for (int i = 0; i < 4; i++) av[i] = *(const bf16x8*)&As[cur][(wm + i * 16 + fr) * 32 + soff];
#pragma unroll
    for (int j = 0; j < 4; j++) bv[j] = *(const bf16x8*)&Bs[cur][(wn + j * 16 + fr) * 32 + soff];
    __builtin_amdgcn_s_setprio(1);
#pragma unroll
    for (int i = 0; i < 4; i++)
#pragma unroll
      for (int j = 0; j < 4; j++)
        acc[i][j] = __builtin_amdgcn_mfma_f32_16x16x32_bf16(av[i], bv[j], acc[i][j], 0, 0, 0);
    __builtin_amdgcn_s_setprio(0);
    __builtin_amdgcn_sched_barrier(0);
  }
#undef STAGE2
#undef ADV2
  asm volatile("s_waitcnt vmcnt(0)" ::: "memory");

  const int crow = (lane >> 4) * 4;
  const int ccol = lane & 15;
#pragma unroll
  for (int j = 0; j < 4; j++) {
    const int gc = n0 + wn + j * 16 + ccol;
    const float bias = b2[e * DDIM + gc];
#pragma unroll
    for (int i = 0; i < 4; i++) {
      const int rr = r0 + wm + i * 16 + crow;
#pragma unroll
      for (int r = 0; r < 4; r++)
        rowout[(size_t)(rr + r) * DDIM + gc] = __float2bfloat16(acc[i][j][r] + bias);
    }
  }
}

// ---------------- combine: out[t] = w0*row0 + w1*row1 ----------------
__global__ __launch_bounds__(256) void combine_kernel(
    const __hip_bfloat16* __restrict__ rowout, const int* __restrict__ tok_row,
    const float* __restrict__ row_weight, float* __restrict__ out) {
  const int idx = blockIdx.x * 256 + threadIdx.x;
  const int t = idx >> 7;
  const int d = (idx & 127) * 8;
  const int r0 = tok_row[t * 2 + 0], r1 = tok_row[t * 2 + 1];
  const float w0 = row_weight[r0], w1 = row_weight[r1];
  bf16x8 a = *(const bf16x8*)&rowout[(size_t)r0 * DDIM + d];
  bf16x8 b = *(const bf16x8*)&rowout[(size_t)r1 * DDIM + d];
  float o[8];
#pragma unroll
  for (int k = 0; k < 8; k++) o[k] = w0 * (float)a[k] + w1 * (float)b[k];
  float* dst = out + (size_t)t * DDIM + d;
  *(float4*)(dst + 0) = make_float4(o[0], o[1], o[2], o[3]);
  *(float4*)(dst + 4) = make_float4(o[4], o[5], o[6], o[7]);
}

// ---------------- lb_loss ----------------
__global__ void finalize_kernel(const float* __restrict__ importance,
                                const int* __restrict__ counts, float* __restrict__ lb_out) {
  if (threadIdx.x == 0 && blockIdx.x == 0) {
    float s = 0.f;
    for (int e = 0; e < NEXP; e++) s += importance[e];
    float lb = 0.f;
    for (int e = 0; e < NEXP; e++)
      lb += (importance[e] / s) * ((float)counts[e] / (float)(NTOK * KTOP));
    lb_out[0] = (float)NEXP * lb;
  }
}

// ---------------- launch ----------------
extern "C" void kernel_launch(void* const* d_in, const int* in_sizes, int n_in,
                              void* d_out, int out_size, void* d_ws, size_t ws_size,
                              hipStream_t stream) {
  (void)in_sizes; (void)n_in; (void)out_size; (void)ws_size;
  const float* x  = (const float*)d_in[0];
  const float* Wg = (const float*)d_in[1];
  const float* bg = (const float*)d_in[2];
  const float* W1 = (const float*)d_in[3];
  const float* b1 = (const float*)d_in[4];
  const float* W2 = (const float*)d_in[5];
  const float* b2 = (const float*)d_in[6];
  float* out = (float*)d_out;

  char* ws = (char*)d_ws;
  __hip_bfloat16* xb     = (__hip_bfloat16*)(ws + XB_OFF);
  __hip_bfloat16* w1t    = (__hip_bfloat16*)(ws + W1T_OFF);
  __hip_bfloat16* rowout = (__hip_bfloat16*)(ws + ROWOUT_OFF);
  __hip_bfloat16* w2t    = (__hip_bfloat16*)(ws + W2T_OFF);
  __hip_bfloat16* hb     = (__hip_bfloat16*)(ws + HB_OFF);
  int*   row_token  = (int*)(ws + ROWTOK_OFF);
  float* row_weight = (float*)(ws + ROWW_OFF);
  int*   tok_e   = (int*)(ws + TOKE_OFF);
  float* tok_w   = (float*)(ws + TOKW_OFF);
  int*   tok_row = (int*)(ws + TOKROW_OFF);
  int*   tile_e  = (int*)(ws + TILEE_OFF);
  int*   counts  = (int*)(ws + CNT_OFF);
  int*   pos     = (int*)(ws + POS_OFF);
  float* importance = (float*)(ws + IMP_OFF);
  int*   meta    = (int*)(ws + META_OFF);

  init_kernel<<<1, 64, 0, stream>>>(counts, importance);
  cast_x_kernel<<<NTOK * DDIM / 4 / 256, 256, 0, stream>>>(x, xb);
  transpose_cast_kernel<<<dim3(HDIM / 64, DDIM / 64, NEXP), 256, 0, stream>>>(W1, w1t, DDIM, HDIM);
  transpose_cast_kernel<<<dim3(DDIM / 64, HDIM / 64, NEXP), 256, 0, stream>>>(W2, w2t, HDIM, DDIM);
  gating_kernel<<<NTOK / 32, 256, 0, stream>>>(x, Wg, bg, tok_e, tok_w, counts, importance);
  offsets_kernel<<<1, 256, 0, stream>>>(counts, pos, tile_e, meta, row_token);
  scatter_kernel<<<NTOK / 256, 256, 0, stream>>>(tok_e, tok_w, pos, row_token, row_weight, tok_row);
  gemm1_kernel<<<dim3(HDIM / 128, MAXTILES), 256, 0, stream>>>(xb, w1t, b1, hb, row_token, tile_e, meta);
  gemm2_kernel<<<dim3((DDIM / 128) * MAXTILES), 256, 0, stream>>>(hb, w2t, b2, rowout, tile_e, meta);
  combine_kernel<<<NTOK * 128 / 256, 256, 0, stream>>>(rowout, tok_row, row_weight, out);
  finalize_kernel<<<1, 64, 0, stream>>>(importance, counts, out + (size_t)NTOK * DDIM);
}

// Round 2
// 839.148 us; speedup vs baseline: 1.0416x; 1.0416x over previous
//
#include <hip/hip_runtime.h>
#include <hip/hip_bf16.h>
#include <math.h>

#define NTOK 8192
#define DDIM 1024
#define HDIM 4096
#define NEXP 8
#define KTOP 2
#define MAXROWS 17408   /* 16384 + 8*128 */
#define MAXTILES 136

typedef __bf16 bf16x8 __attribute__((ext_vector_type(8)));
typedef float f32x4 __attribute__((ext_vector_type(4)));

#define GAS __attribute__((address_space(1)))
#define LAS __attribute__((address_space(3)))

__device__ __forceinline__ void async16(const void* g, void* l) {
  __builtin_amdgcn_global_load_lds((GAS void*)g, (LAS void*)l, 16, 0, 0);
}

// ---------------- workspace layout (bytes) ----------------
#define XB_OFF     ((size_t)0)
#define W1T_OFF    (XB_OFF + (size_t)NTOK*DDIM*2)
#define ROWOUT_OFF W1T_OFF              /* w1t dead after gemm1; rowout 35.7MB < 64MB */
#define W2T_OFF    (W1T_OFF + (size_t)NEXP*DDIM*HDIM*2)
#define HB_OFF     (W2T_OFF + (size_t)NEXP*HDIM*DDIM*2)
#define ROWTOK_OFF (HB_OFF + (size_t)MAXROWS*HDIM*2)
#define ROWW_OFF   (ROWTOK_OFF + (size_t)MAXROWS*4)
#define TOKE_OFF   (ROWW_OFF + (size_t)MAXROWS*4)
#define TOKW_OFF   (TOKE_OFF + (size_t)NTOK*KTOP*4)
#define TOKROW_OFF (TOKW_OFF + (size_t)NTOK*KTOP*4)
#define TILEE_OFF  (TOKROW_OFF + (size_t)NTOK*KTOP*4)
#define CNT_OFF    (TILEE_OFF + (size_t)256*4)
#define POS_OFF    (CNT_OFF + 64)
#define IMP_OFF    (POS_OFF + 64)
#define META_OFF   (IMP_OFF + 64)

// ---------------- small utility kernels ----------------
__global__ void init_kernel(int* counts, float* importance) {
  if (threadIdx.x < NEXP) { counts[threadIdx.x] = 0; importance[threadIdx.x] = 0.f; }
}

__global__ void cast_x_kernel(const float* __restrict__ src, __hip_bfloat16* __restrict__ dst) {
  size_t i = ((size_t)blockIdx.x * blockDim.x + threadIdx.x) * 4;
  if (i < (size_t)NTOK * DDIM) {
    float4 v = *(const float4*)(src + i);
    dst[i + 0] = __float2bfloat16(v.x);
    dst[i + 1] = __float2bfloat16(v.y);
    dst[i + 2] = __float2bfloat16(v.z);
    dst[i + 3] = __float2bfloat16(v.w);
  }
}

// per-expert transpose+cast: src [E][R][C] fp32 -> dst [E][C][R] bf16
__global__ __launch_bounds__(256) void transpose_cast_kernel(
    const float* __restrict__ src, __hip_bfloat16* __restrict__ dst, int R, int C) {
  __shared__ float tile[64][65];
  const int e = blockIdx.z;
  const float* s = src + (size_t)e * R * C;
  __hip_bfloat16* d = dst + (size_t)e * R * C;
  const int c0 = blockIdx.x * 64, r0 = blockIdx.y * 64;
  const int tc = (threadIdx.x & 15) * 4;
  const int tr = threadIdx.x >> 4;
#pragma unroll
  for (int p = 0; p < 4; ++p) {
    float4 v = *(const float4*)&s[(size_t)(r0 + tr + p * 16) * C + c0 + tc];
    tile[tr + p * 16][tc + 0] = v.x;
    tile[tr + p * 16][tc + 1] = v.y;
    tile[tr + p * 16][tc + 2] = v.z;
    tile[tr + p * 16][tc + 3] = v.w;
  }
  __syncthreads();
  const int oc = threadIdx.x >> 4;
  const int orr = (threadIdx.x & 15) * 4;
#pragma unroll
  for (int p = 0; p < 4; ++p) {
    const int c = oc + p * 16;
    __hip_bfloat16 tmp[4];
    tmp[0] = __float2bfloat16(tile[orr + 0][c]);
    tmp[1] = __float2bfloat16(tile[orr + 1][c]);
    tmp[2] = __float2bfloat16(tile[orr + 2][c]);
    tmp[3] = __float2bfloat16(tile[orr + 3][c]);
    *(ushort4*)&d[(size_t)(c0 + c) * R + r0 + orr] = *(ushort4*)tmp;
  }
}

// ---------------- gating ----------------
__global__ __launch_bounds__(256) void gating_kernel(
    const float* __restrict__ x, const float* __restrict__ Wg, const float* __restrict__ bg,
    int* __restrict__ tok_e, float* __restrict__ tok_w,
    int* __restrict__ counts, float* __restrict__ importance) {
  const int tid = threadIdx.x, wid = tid >> 6, lane = tid & 63;
  const int t = blockIdx.x * 32 + wid * 8 + (lane >> 3);
  const int e = lane & 7;
  const float* xr = x + (size_t)t * DDIM;
  double dot = 0.0;
  for (int d = 0; d < DDIM; d += 4) {
    float4 xv = *(const float4*)(xr + d);
    dot += (double)xv.x * (double)Wg[(d + 0) * NEXP + e];
    dot += (double)xv.y * (double)Wg[(d + 1) * NEXP + e];
    dot += (double)xv.z * (double)Wg[(d + 2) * NEXP + e];
    dot += (double)xv.w * (double)Wg[(d + 3) * NEXP + e];
  }
  double logit = dot + (double)bg[e];
  double m = logit;
  for (int off = 1; off < 8; off <<= 1) {
    double o = __shfl_xor(m, off, 64);
    m = o > m ? o : m;
  }
  double p = exp(logit - m);
  double s = p;
  for (int off = 1; off < 8; off <<= 1) s += __shfl_xor(s, off, 64);
  float prob = (float)(p / s);

  __shared__ float imp[NEXP];
  __shared__ int cnt[NEXP];
  if (tid < NEXP) { imp[tid] = 0.f; cnt[tid] = 0; }
  __syncthreads();
  atomicAdd(&imp[e], prob);

  float bp = prob; int be = e;
  for (int off = 1; off < 8; off <<= 1) {
    float op = __shfl_xor(bp, off, 64); int oe = __shfl_xor(be, off, 64);
    if (op > bp || (op == bp && oe < be)) { bp = op; be = oe; }
  }
  float p2 = (e == be) ? -1.f : prob;
  float sp = p2; int se = e;
  for (int off = 1; off < 8; off <<= 1) {
    float op = __shfl_xor(sp, off, 64); int oe = __shfl_xor(se, off, 64);
    if (op > sp || (op == sp && oe < se)) { sp = op; se = oe; }
  }
  if (e == 0) {
    float tsum = bp + sp;
    tok_e[t * 2 + 0] = be; tok_e[t * 2 + 1] = se;
    tok_w[t * 2 + 0] = bp / tsum; tok_w[t * 2 + 1] = sp / tsum;
    atomicAdd(&cnt[be], 1); atomicAdd(&cnt[se], 1);
  }
  __syncthreads();
  if (tid < NEXP) {
    atomicAdd(&counts[tid], cnt[tid]);
    atomicAdd(&importance[tid], imp[tid]);
  }
}

// ---------------- routing ----------------
__global__ void offsets_kernel(const int* __restrict__ counts, int* pos, int* tile_expert,
                               int* meta, int* row_token) {
  if (threadIdx.x == 0) {
    int pb = 0, tb = 0;
    for (int e = 0; e < NEXP; e++) {
      pos[e] = pb;
      int tiles = (counts[e] + 127) >> 7;
      for (int tt = 0; tt < tiles; ++tt) tile_expert[tb + tt] = e;
      pb += tiles * 128; tb += tiles;
    }
    meta[0] = tb;
  }
  __syncthreads();
  for (int i = threadIdx.x; i < MAXROWS; i += blockDim.x) row_token[i] = -1;
}

__global__ void scatter_kernel(const int* __restrict__ tok_e, const float* __restrict__ tok_w,
                               int* __restrict__ pos, int* __restrict__ row_token,
                               float* __restrict__ row_weight, int* __restrict__ tok_row) {
  __shared__ int lcnt[NEXP], lbase[NEXP];
  const int t = blockIdx.x * 256 + threadIdx.x;
  if (threadIdx.x < NEXP) lcnt[threadIdx.x] = 0;
  __syncthreads();
  const int e0 = tok_e[t * 2 + 0], e1 = tok_e[t * 2 + 1];
  const int s0 = atomicAdd(&lcnt[e0], 1);
  const int s1 = atomicAdd(&lcnt[e1], 1);
  __syncthreads();
  if (threadIdx.x < NEXP) lbase[threadIdx.x] = atomicAdd(&pos[threadIdx.x], lcnt[threadIdx.x]);
  __syncthreads();
  int r0 = lbase[e0] + s0; row_token[r0] = t; row_weight[r0] = tok_w[t * 2 + 0]; tok_row[t * 2 + 0] = r0;
  int r1 = lbase[e1] + s1; row_token[r1] = t; row_weight[r1] = tok_w[t * 2 + 1]; tok_row[t * 2 + 1] = r1;
}

// ---------------- phase-interleaved 8-wave GEMM (128x256 tile, BK=64) ----------------
// 8 waves as 2(M) x 4(N); per-wave output 64x64 (acc[4][4]).
// LDS: A[2][128][64] + B[2][256][64] bf16 = 96 KiB, st-XOR swizzled (slot ^= row&7).
// Schedule per K-tile kt (2 phases, 2 barriers each):
//  p0: ds_read A(kt)+B_lo(kt); stage B_hi(kt+1)->nxt; bar; lgkm0; 16 MFMA; vmcnt(6); bar
//  p1: ds_read B_hi(kt);       stage A(kt+2)+B_lo(kt+2)->cur; bar; lgkm0; 16 MFMA; vmcnt(6); bar
// Stage lead = 3 half-tiles, vmcnt floor 6 in flight (T4) -- never drains to 0 in-loop.
template<int NDIM, int KDIM, int NCOLT, bool GATHER, bool RELU>
__global__ __launch_bounds__(512, 2) void moe_gemm_kernel(
    const __hip_bfloat16* __restrict__ Ag, const __hip_bfloat16* __restrict__ Bg,
    const float* __restrict__ bias, __hip_bfloat16* __restrict__ Cg,
    const int* __restrict__ row_token, const int* __restrict__ tile_expert,
    const int* __restrict__ meta) {
  // XCD swizzle: contiguous v-range per XCD (grid % 8 == 0)
  const int id = blockIdx.x;
  const int v = (id & 7) * ((int)gridDim.x >> 3) + (id >> 3);
  const int ty = v / NCOLT, cx = v % NCOLT;
  if (ty >= meta[0]) return;
  const int e = tile_expert[ty];
  const int r0 = ty * 128;
  const int n0 = cx * 256;
  const int tid = threadIdx.x, wid = tid >> 6, lane = tid & 63;
  const int wm = wid >> 2, wn = wid & 3;   // 2 x 4 waves
  const int fr = lane & 15;
  const int NT = KDIM / 64;

  __shared__ __align__(16) __hip_bfloat16 Al[2][128][64];
  __shared__ __align__(16) __hip_bfloat16 Bl[2][256][64];

  // --- staging setup: chunk c = wid*2+i covers 8 rows x 128B; lane l -> row l>>3, slot l&7
  // inverse-swizzled global source group: gsrc = (l&7) ^ (row&7) = (l&7) ^ (l>>3)
  const int l8 = lane >> 3;
  const int gsrc = (lane & 7) ^ l8;
  const __hip_bfloat16* aptr[2];
  const __hip_bfloat16* bptr0[2];
  const __hip_bfloat16* bptr1[2];
#pragma unroll
  for (int i = 0; i < 2; ++i) {
    const int c = wid * 2 + i;
    const int arow = r0 + c * 8 + l8;
    if (GATHER) {
      int t = row_token[arow]; if (t < 0) t = 0;
      aptr[i] = Ag + (size_t)t * KDIM + gsrc * 8;
    } else {
      aptr[i] = Ag + (size_t)arow * KDIM + gsrc * 8;
    }
    bptr0[i] = Bg + ((size_t)e * NDIM + n0 + c * 8 + l8) * KDIM + gsrc * 8;
    bptr1[i] = bptr0[i] + (size_t)128 * KDIM;
  }

#define ST_A(buf, kk)  do { _Pragma("unroll") for (int i = 0; i < 2; ++i) \
    async16(aptr[i]  + (kk) * 64, &Al[buf][(wid * 2 + i) * 8][0]); } while (0)
#define ST_B0(buf, kk) do { _Pragma("unroll") for (int i = 0; i < 2; ++i) \
    async16(bptr0[i] + (kk) * 64, &Bl[buf][(wid * 2 + i) * 8][0]); } while (0)
#define ST_B1(buf, kk) do { _Pragma("unroll") for (int i = 0; i < 2; ++i) \
    async16(bptr1[i] + (kk) * 64, &Bl[buf][128 + (wid * 2 + i) * 8][0]); } while (0)

  // --- read-side swizzled slot (elem offset): s(krep) = ((krep*4 + (lane>>4)) ^ (lane&7)) * 8
  const int g4 = lane >> 4, r7 = lane & 7;
  const int s0e = ((0 + g4) ^ r7) * 8;
  const int s1e = ((4 + g4) ^ r7) * 8;

  f32x4 acc[4][4] = {};

  // prologue: A(0),B0(0),B1(0),A(1),B0(1) = 10 loads; drain 4 oldest
  ST_A(0, 0); ST_B0(0, 0); ST_B1(0, 0);
  ST_A(1, 1); ST_B0(1, 1);
  asm volatile("s_waitcnt vmcnt(6)" ::: "memory");
  __builtin_amdgcn_sched_barrier(0);
  __builtin_amdgcn_s_barrier();

#pragma unroll 1
  for (int kt = 0; kt < NT; ++kt) {
    const int cur = kt & 1, nxt = cur ^ 1;
    const int kk1 = (kt + 1 < NT) ? kt + 1 : NT - 1;
    const int kk2 = (kt + 2 < NT) ? kt + 2 : NT - 1;
    bf16x8 av[4][2], bv[2][2];
    // ---------- phase 0: A + B rows [0,128) ----------
#pragma unroll
    for (int mi = 0; mi < 4; ++mi) {
      av[mi][0] = *(const bf16x8*)&Al[cur][wm * 64 + mi * 16 + fr][s0e];
      av[mi][1] = *(const bf16x8*)&Al[cur][wm * 64 + mi * 16 + fr][s1e];
    }
#pragma unroll
    for (int j = 0; j < 2; ++j) {
      bv[j][0] = *(const bf16x8*)&Bl[cur][wn * 32 + j * 16 + fr][s0e];
      bv[j][1] = *(const bf16x8*)&Bl[cur][wn * 32 + j * 16 + fr][s1e];
    }
    ST_B1(nxt, kk1);
    __builtin_amdgcn_s_barrier();
    asm volatile("s_waitcnt lgkmcnt(0)" ::: "memory");
    __builtin_amdgcn_sched_barrier(0);
    __builtin_amdgcn_s_setprio(1);
#pragma unroll
    for (int mi = 0; mi < 4; ++mi)
#pragma unroll
      for (int j = 0; j < 2; ++j)
#pragma unroll
        for (int k = 0; k < 2; ++k)
          acc[mi][j] = __builtin_amdgcn_mfma_f32_16x16x32_bf16(av[mi][k], bv[j][k], acc[mi][j], 0, 0, 0);
    __builtin_amdgcn_s_setprio(0);
    asm volatile("s_waitcnt vmcnt(6)" ::: "memory");
    __builtin_amdgcn_sched_barrier(0);
    __builtin_amdgcn_s_barrier();
    // ---------- phase 1: B rows [128,256) ----------
#pragma unroll
    for (int j = 0; j < 2; ++j) {
      bv[j][0] = *(const bf16x8*)&Bl[cur][128 + wn * 32 + j * 16 + fr][s0e];
      bv[j][1] = *(const bf16x8*)&Bl[cur][128 + wn * 32 + j * 16 + fr][s1e];
    }
    ST_A(cur, kk2); ST_B0(cur, kk2);
    __builtin_amdgcn_s_barrier();
    asm volatile("s_waitcnt lgkmcnt(0)" ::: "memory");
    __builtin_amdgcn_sched_barrier(0);
    __builtin_amdgcn_s_setprio(1);
#pragma unroll
    for (int mi = 0; mi < 4; ++mi)
#pragma unroll
      for (int j = 0; j < 2; ++j)
#pragma unroll
        for (int k = 0; k < 2; ++k)
          acc[mi][2 + j] = __builtin_amdgcn_mfma_f32_16x16x32_bf16(av[mi][k], bv[j][k], acc[mi][2 + j], 0, 0, 0);
    __builtin_amdgcn_s_setprio(0);
    asm volatile("s_waitcnt vmcnt(6)" ::: "memory");
    __builtin_amdgcn_sched_barrier(0);
    __builtin_amdgcn_s_barrier();
  }
#undef ST_A
#undef ST_B0
#undef ST_B1
  asm volatile("s_waitcnt vmcnt(0)" ::: "memory");

  // epilogue: C row = r0 + wm*64 + mi*16 + (lane>>4)*4 + r; col = n0 + (nj>>1)*128 + wn*32 + (nj&1)*16 + (lane&15)
  const int crow = (lane >> 4) * 4;
  const int ccol = lane & 15;
#pragma unroll
  for (int nj = 0; nj < 4; ++nj) {
    const int gc = n0 + (nj >> 1) * 128 + wn * 32 + (nj & 1) * 16 + ccol;
    const float bv_ = bias[e * NDIM + gc];
#pragma unroll
    for (int mi = 0; mi < 4; ++mi) {
      const int grb = r0 + wm * 64 + mi * 16 + crow;
#pragma unroll
      for (int r = 0; r < 4; ++r) {
        float vv = acc[mi][nj][r] + bv_;
        if (RELU) vv = vv > 0.f ? vv : 0.f;
        Cg[(size_t)(grb + r) * NDIM + gc] = __float2bfloat16(vv);
      }
    }
  }
}

// ---------------- combine: out[t] = w0*row0 + w1*row1 ----------------
__global__ __launch_bounds__(256) void combine_kernel(
    const __hip_bfloat16* __restrict__ rowout, const int* __restrict__ tok_row,
    const float* __restrict__ row_weight, float* __restrict__ out) {
  const int idx = blockIdx.x * 256 + threadIdx.x;
  const int t = idx >> 7;
  const int d = (idx & 127) * 8;
  const int r0 = tok_row[t * 2 + 0], r1 = tok_row[t * 2 + 1];
  const float w0 = row_weight[r0], w1 = row_weight[r1];
  bf16x8 a = *(const bf16x8*)&rowout[(size_t)r0 * DDIM + d];
  bf16x8 b = *(const bf16x8*)&rowout[(size_t)r1 * DDIM + d];
  float o[8];
#pragma unroll
  for (int k = 0; k < 8; k++) o[k] = w0 * (float)a[k] + w1 * (float)b[k];
  float* dst = out + (size_t)t * DDIM + d;
  *(float4*)(dst + 0) = make_float4(o[0], o[1], o[2], o[3]);
  *(float4*)(dst + 4) = make_float4(o[4], o[5], o[6], o[7]);
}

// ---------------- lb_loss ----------------
__global__ void finalize_kernel(const float* __restrict__ importance,
                                const int* __restrict__ counts, float* __restrict__ lb_out) {
  if (threadIdx.x == 0 && blockIdx.x == 0) {
    float s = 0.f;
    for (int e = 0; e < NEXP; e++) s += importance[e];
    float lb = 0.f;
    for (int e = 0; e < NEXP; e++)
      lb += (importance[e] / s) * ((float)counts[e] / (float)(NTOK * KTOP));
    lb_out[0] = (float)NEXP * lb;
  }
}

// ---------------- launch ----------------
extern "C" void kernel_launch(void* const* d_in, const int* in_sizes, int n_in,
                              void* d_out, int out_size, void* d_ws, size_t ws_size,
                              hipStream_t stream) {
  (void)in_sizes; (void)n_in; (void)out_size; (void)ws_size;
  const float* x  = (const float*)d_in[0];
  const float* Wg = (const float*)d_in[1];
  const float* bg = (const float*)d_in[2];
  const float* W1 = (const float*)d_in[3];
  const float* b1 = (const float*)d_in[4];
  const float* W2 = (const float*)d_in[5];
  const float* b2 = (const float*)d_in[6];
  float* out = (float*)d_out;

  char* ws = (char*)d_ws;
  __hip_bfloat16* xb     = (__hip_bfloat16*)(ws + XB_OFF);
  __hip_bfloat16* w1t    = (__hip_bfloat16*)(ws + W1T_OFF);
  __hip_bfloat16* rowout = (__hip_bfloat16*)(ws + ROWOUT_OFF);
  __hip_bfloat16* w2t    = (__hip_bfloat16*)(ws + W2T_OFF);
  __hip_bfloat16* hb     = (__hip_bfloat16*)(ws + HB_OFF);
  int*   row_token  = (int*)(ws + ROWTOK_OFF);
  float* row_weight = (float*)(ws + ROWW_OFF);
  int*   tok_e   = (int*)(ws + TOKE_OFF);
  float* tok_w   = (float*)(ws + TOKW_OFF);
  int*   tok_row = (int*)(ws + TOKROW_OFF);
  int*   tile_e  = (int*)(ws + TILEE_OFF);
  int*   counts  = (int*)(ws + CNT_OFF);
  int*   pos     = (int*)(ws + POS_OFF);
  float* importance = (float*)(ws + IMP_OFF);
  int*   meta    = (int*)(ws + META_OFF);

  init_kernel<<<1, 64, 0, stream>>>(counts, importance);
  cast_x_kernel<<<NTOK * DDIM / 4 / 256, 256, 0, stream>>>(x, xb);
  transpose_cast_kernel<<<dim3(HDIM / 64, DDIM / 64, NEXP), 256, 0, stream>>>(W1, w1t, DDIM, HDIM);
  transpose_cast_kernel<<<dim3(DDIM / 64, HDIM / 64, NEXP), 256, 0, stream>>>(W2, w2t, HDIM, DDIM);
  gating_kernel<<<NTOK / 32, 256, 0, stream>>>(x, Wg, bg, tok_e, tok_w, counts, importance);
  offsets_kernel<<<1, 256, 0, stream>>>(counts, pos, tile_e, meta, row_token);
  scatter_kernel<<<NTOK / 256, 256, 0, stream>>>(tok_e, tok_w, pos, row_token, row_weight, tok_row);
  // gemm1: h = relu(x @ W1[e] + b1[e])   [gather A, N=4096, K=1024]
  moe_gemm_kernel<HDIM, DDIM, HDIM / 256, true, true>
      <<<MAXTILES * (HDIM / 256), 512, 0, stream>>>(xb, w1t, b1, hb, row_token, tile_e, meta);
  // gemm2: rowout = h @ W2[e] + b2[e]    [direct A, N=1024, K=4096]
  moe_gemm_kernel<DDIM, HDIM, DDIM / 256, false, false>
      <<<MAXTILES * (DDIM / 256), 512, 0, stream>>>(hb, w2t, b2, rowout, row_token, tile_e, meta);
  combine_kernel<<<NTOK * 128 / 256, 256, 0, stream>>>(rowout, tok_row, row_weight, out);
  finalize_kernel<<<1, 64, 0, stream>>>(importance, counts, out + (size_t)NTOK * DDIM);
}